// Round 3
// baseline (659.910 us; speedup 1.0000x reference)
//
#include <hip/hip_runtime.h>
#include <math.h>

#define Bq 64
#define Hq 256
#define Lq 1024
#define HLq (Hq*Lq)        // 262144
#define BHLq (Bq*Hq*Lq)    // 16777216
#define HNq (Hq*64)        // 16384

typedef __attribute__((ext_vector_type(8))) short bf16x8;
typedef __attribute__((ext_vector_type(4))) float f32x4;

__device__ __forceinline__ float sigmoidf_(float x){ return 1.f/(1.f+expf(-x)); }
__device__ __forceinline__ unsigned short f2bf(float f){
  unsigned u = __float_as_uint(f);
  u += 0x7FFF + ((u>>16)&1);
  return (unsigned short)(u>>16);
}
__device__ __forceinline__ float bf2f(unsigned short h){ return __uint_as_float(((unsigned)h)<<16); }

// ---------------- K1a: sinusoidal embedding + SiLU -> Sb (64 x 1024 bf16)
__global__ void k_emb(const int* __restrict__ tptr, unsigned short* __restrict__ Sb){
  const int b = blockIdx.x;
  const float tv = (float)tptr[b];
  const float ci = -logf(10000.f) / 511.f;
  const int i0 = threadIdx.x * 4;
  unsigned short pk[4];
  #pragma unroll
  for (int q = 0; q < 4; ++q){
    int i = i0 + q;
    float f = expf(ci * (float)(i & 511));
    float arg = tv * f;
    float val = (i < 512) ? sinf(arg) : cosf(arg);
    pk[q] = f2bf(val * sigmoidf_(val));
  }
  uint2 v;
  v.x = (unsigned)pk[0] | ((unsigned)pk[1] << 16);
  v.y = (unsigned)pk[2] | ((unsigned)pk[3] << 16);
  *(uint2*)(Sb + (size_t)b*1024 + i0) = v;
}

// ---------------- K1b: scsh[b][o] = Sb[b][:] @ ada_w[o][:] + ada_b[o]  (bf16 MFMA)
// M = o (2048), N = b (64), K = 1024
__global__ __launch_bounds__(256,2) void k_adaG(const unsigned short* __restrict__ Sb,
        const float* __restrict__ ada_w, const float* __restrict__ ada_b,
        float* __restrict__ scsh){
  __shared__ unsigned short Ws[64][72];
  __shared__ unsigned short Ss[64][72];
  const int tid = threadIdx.x;
  const int o0 = blockIdx.x * 64;
  const int lane = tid & 63, w = tid>>6, ln = lane&15, quad = lane>>4;
  f32x4 acc[4] = {};
  for (int kc = 0; kc < 1024; kc += 64){
    __syncthreads();
    { // stage 64 o x 64 k of ada_w, fp32 -> bf16
      int o = tid & 63;
      int i = (tid >> 6) * 16;
      const float* wsrc = ada_w + (size_t)(o0+o)*1024 + kc + i;
      unsigned pk[8];
      #pragma unroll
      for (int r=0;r<8;++r) pk[r] = (unsigned)f2bf(wsrc[2*r]) | ((unsigned)f2bf(wsrc[2*r+1])<<16);
      uint4* dst = (uint4*)&Ws[o][i];
      dst[0] = make_uint4(pk[0],pk[1],pk[2],pk[3]);
      dst[1] = make_uint4(pk[4],pk[5],pk[6],pk[7]);
    }
    { // stage 64 b x 64 k of Sb (already bf16)
      int b = tid & 63;
      int i = (tid >> 6) * 16;
      const uint4* src = (const uint4*)(Sb + (size_t)b*1024 + kc + i);
      uint4* dst = (uint4*)&Ss[b][i];
      dst[0] = src[0];
      dst[1] = src[1];
    }
    __syncthreads();
    #pragma unroll
    for (int ks = 0; ks < 2; ++ks){
      int kk = ks*32 + quad*8;
      bf16x8 af = *(const bf16x8*)&Ws[w*16+ln][kk];
      #pragma unroll
      for (int nt=0; nt<4; ++nt){
        bf16x8 bv = *(const bf16x8*)&Ss[nt*16+ln][kk];
        acc[nt] = __builtin_amdgcn_mfma_f32_16x16x32_bf16(af, bv, acc[nt], 0,0,0);
      }
    }
  }
  #pragma unroll
  for (int reg=0; reg<4; ++reg){
    int o = o0 + w*16 + quad*4 + reg;
    float bo = ada_b[o];
    #pragma unroll
    for (int nt=0; nt<4; ++nt){
      int b = nt*16 + ln;
      scsh[b*2048 + o] = acc[nt][reg] + bo;
    }
  }
}

// ---------------- K2: AdaLayerNorm over L per (b,h) row -> Ax (fp32)
__global__ void k_adaln(const float* __restrict__ x, const float* __restrict__ scsh,
                        float* __restrict__ A){
  const int bid = blockIdx.x;        // b*H + h
  const int b = bid >> 8;
  const int tid = threadIdx.x;
  const float4* row = (const float4*)(x + (size_t)bid*1024);
  float4 v = row[tid];
  float s = v.x+v.y+v.z+v.w;
  float ss = v.x*v.x+v.y*v.y+v.z*v.z+v.w*v.w;
  #pragma unroll
  for (int off=32; off; off>>=1){ s += __shfl_xor(s,off); ss += __shfl_xor(ss,off); }
  __shared__ float rs_[4], rss_[4];
  int lane = tid & 63, w = tid >> 6;
  if (!lane){ rs_[w]=s; rss_[w]=ss; }
  __syncthreads();
  s  = rs_[0]+rs_[1]+rs_[2]+rs_[3];
  ss = rss_[0]+rss_[1]+rss_[2]+rss_[3];
  float mean = s * (1.f/1024.f);
  float var  = ss*(1.f/1024.f) - mean*mean;
  float rstd = rsqrtf(var + 1e-5f);
  float4 sc = ((const float4*)(scsh + b*2048))[tid];
  float4 sh = ((const float4*)(scsh + b*2048 + 1024))[tid];
  float4 o;
  o.x = (v.x-mean)*rstd*(1.f+sc.x) + sh.x;
  o.y = (v.y-mean)*rstd*(1.f+sc.y) + sh.y;
  o.z = (v.z-mean)*rstd*(1.f+sc.z) + sh.z;
  o.w = (v.w-mean)*rstd*(1.f+sc.w) + sh.w;
  ((float4*)(A + (size_t)bid*1024))[tid] = o;
}

// ---------------- K3: channel LayerNorm over H per (b,l) -> z in bf16
__global__ void k_chln(const float* __restrict__ A, const float* __restrict__ nw,
                       const float* __restrict__ nb, unsigned short* __restrict__ Zb){
  const int b = blockIdx.y;
  const int l = blockIdx.x*256 + threadIdx.x;
  const float* base = A + (size_t)b*HLq + l;
  float s=0.f, ss=0.f;
  for (int h=0; h<256; ++h){ float v = base[h*1024]; s+=v; ss+=v*v; }
  float mean = s*(1.f/256.f);
  float var  = ss*(1.f/256.f) - mean*mean;
  float rstd = rsqrtf(var+1e-5f);
  unsigned short* zb = Zb + (size_t)b*HLq + l;
  for (int h=0; h<256; ++h){
    float v = base[h*1024];
    zb[h*1024] = f2bf((v-mean)*rstd*nw[h] + nb[h]);
  }
}

// ---------------- K4: SSM kernels K0/K1 (2,H,L) via direct Vandermonde sum (fp32)
__global__ void k_ssmk(const float* __restrict__ log_dt, const float* __restrict__ A_re,
                       const float* __restrict__ A_im, const float* __restrict__ C_re,
                       const float* __restrict__ C_im, float* __restrict__ Kbuf){
  const int h = blockIdx.y;
  const int tid = threadIdx.x;
  __shared__ float dre[64], dim_[64], c0r[64], c0i[64], c1r[64], c1i[64];
  if (tid < 64){
    int n = tid;
    float dt = expf(log_dt[h]);
    float Ar = -expf(A_re[h*64+n]);
    float Ai = A_im[h*64+n];
    float dr = dt*Ar, di = dt*Ai;
    float er = expf(dr);
    float dAr = er*cosf(di), dAi = er*sinf(di);
    float den = Ar*Ar + Ai*Ai;
    float nr = dAr - 1.f, ni = dAi;
    float qr = (nr*Ar + ni*Ai)/den;
    float qi = (ni*Ar - nr*Ai)/den;
    float C0r = C_re[h*64+n],       C0i = C_im[h*64+n];
    float C1r = C_re[HNq + h*64+n], C1i = C_im[HNq + h*64+n];
    c0r[n] = C0r*qr - C0i*qi; c0i[n] = C0r*qi + C0i*qr;
    c1r[n] = C1r*qr - C1i*qi; c1i[n] = C1r*qi + C1i*qr;
    dre[n] = dr; dim_[n] = di;
  }
  __syncthreads();
  int l = blockIdx.x*256 + tid;
  float lf = (float)l;
  float a0=0.f, a1=0.f;
  for (int n=0;n<64;++n){
    float e  = expf(lf*dre[n]);
    float ph = lf*dim_[n];
    float wr = e*cosf(ph), wi = e*sinf(ph);
    a0 += c0r[n]*wr - c0i[n]*wi;
    a1 += c1r[n]*wr - c1i[n]*wi;
  }
  Kbuf[h*1024 + l]       = 2.f*a0;
  Kbuf[HLq + h*1024 + l] = 2.f*a1;
}

// ---------------- K5: bidirectional Toeplitz conv via bf16 MFMA + D*z + GELU -> Cb bf16
__global__ __launch_bounds__(256,2) void k_conv(const unsigned short* __restrict__ Zb,
        const float* __restrict__ Kbuf, const float* __restrict__ Dp,
        unsigned short* __restrict__ Cb){
  __shared__ unsigned short kcopy[8][2056];   // stride 2056 el = 1028 dw = 4 mod 32 (bank spread)
  __shared__ unsigned short As[64][136];      // z tile, Kc=128, +8 pad
  const int tid = threadIdx.x;
  const int h  = blockIdx.y;
  const int l0 = blockIdx.x * 512;
  const float* K0 = Kbuf + h*1024;
  const float* K1 = Kbuf + HLq + h*1024;
  // krev[p] = kf[2046-p]; kf[1023+d] = d>=0 ? K0[d] : K1[-d-1]; copy[s][i] = krev[i+s]
  for (int idx = tid; idx < 8*2056; idx += 256){
    int s = idx / 2056;
    int i = idx - s*2056;
    int q = 2046 - i - s;
    float v = 0.f;
    if (q >= 0) v = (q >= 1023) ? K0[q-1023] : K1[1022-q];
    kcopy[s][i] = f2bf(v);
  }
  const int lane = tid & 63;
  const int w    = tid >> 6;
  const int ln   = lane & 15;
  const int quad = lane >> 4;
  int kofs[8];
  #pragma unroll
  for (int nt=0; nt<8; ++nt){
    int l = l0 + w*128 + nt*16 + ln;
    int d = 1023 - l;              // krev base = d + j
    int s = d & 7;
    kofs[nt] = s*2056 + (d - s) + quad*8;   // 16B-aligned element offset
  }
  const unsigned short* kbase = &kcopy[0][0];
  f32x4 acc[4][8] = {};
  for (int c = 0; c < 8; ++c){
    __syncthreads();
    #pragma unroll
    for (int pass = 0; pass < 4; ++pass){
      int b = pass*16 + (tid>>4);
      int col = (tid & 15)*8;
      *(uint4*)&As[b][col] = *(const uint4*)(Zb + ((size_t)b*256 + h)*1024 + c*128 + col);
    }
    __syncthreads();
    #pragma unroll
    for (int ks = 0; ks < 4; ++ks){
      int kk = ks*32 + quad*8;
      bf16x8 af[4];
      #pragma unroll
      for (int mt=0; mt<4; ++mt) af[mt] = *(const bf16x8*)&As[mt*16+ln][kk];
      int jb = c*128 + ks*32;
      bf16x8 bv[8];
      #pragma unroll
      for (int nt=0; nt<8; ++nt) bv[nt] = *(const bf16x8*)(kbase + kofs[nt] + jb);
      #pragma unroll
      for (int mt=0; mt<4; ++mt)
        #pragma unroll
        for (int nt=0; nt<8; ++nt)
          acc[mt][nt] = __builtin_amdgcn_mfma_f32_16x16x32_bf16(af[mt], bv[nt], acc[mt][nt], 0,0,0);
    }
  }
  float Dh = Dp[h];
  #pragma unroll
  for (int mt=0; mt<4; ++mt){
    #pragma unroll
    for (int reg=0; reg<4; ++reg){
      int b = mt*16 + quad*4 + reg;
      const unsigned short* zrow = Zb + ((size_t)b*256+h)*1024;
      unsigned short* crow = Cb + ((size_t)b*256+h)*1024;
      #pragma unroll
      for (int nt=0; nt<8; ++nt){
        int l = l0 + w*128 + nt*16 + ln;
        float y = acc[mt][nt][reg] + Dh*bf2f(zrow[l]);
        float g = 0.5f*y*(1.f + erff(y*0.70710678118f));
        crow[l] = f2bf(g);
      }
    }
  }
}

// ---------------- K6: x2 = out_w @ u + out_b + x1 ; g = tanh(x2)*sigmoid(x2)  (bf16 MFMA)
__global__ __launch_bounds__(256,2) void k_gate(const unsigned short* __restrict__ U,
        const float* __restrict__ W, const float* __restrict__ bias,
        const float* __restrict__ Ax, unsigned short* __restrict__ G){
  __shared__ unsigned short Ws[64][72];
  __shared__ unsigned short Us[256][72];
  const int tid = threadIdx.x;
  const int l0 = blockIdx.x * 256;
  const int o0 = blockIdx.y * 64;
  const int b  = blockIdx.z;
  const int lane = tid & 63, w = tid>>6, ln = lane&15, quad = lane>>4;
  f32x4 acc[4][4] = {};
  for (int ch = 0; ch < 4; ++ch){
    int ic0 = ch*64;
    __syncthreads();
    { // Ws: 64 o x 64 i (fp32 -> bf16)
      int o = tid & 63;
      int i = (tid >> 6) * 16;
      const float* wsrc = W + (size_t)(o0+o)*256 + ic0 + i;
      unsigned pk[8];
      #pragma unroll
      for (int r=0;r<8;++r) pk[r] = (unsigned)f2bf(wsrc[2*r]) | ((unsigned)f2bf(wsrc[2*r+1])<<16);
      uint4* dst = (uint4*)&Ws[o][i];
      dst[0] = make_uint4(pk[0],pk[1],pk[2],pk[3]);
      dst[1] = make_uint4(pk[4],pk[5],pk[6],pk[7]);
    }
    // Us: [l][i] = U[b][ic0+i][l0+l]  (transpose staging, 4 i per 8B write)
    #pragma unroll
    for (int it = 0; it < 16; ++it){
      int i4 = (tid>>6) + 4*(it&3);
      int l  = (it>>2)*64 + (tid&63);
      const unsigned short* usrc = U + ((size_t)b*256 + ic0 + i4*4)*1024 + l0 + l;
      unsigned short e0 = usrc[0], e1 = usrc[1024], e2 = usrc[2048], e3 = usrc[3072];
      uint2 val; val.x = (unsigned)e0 | ((unsigned)e1<<16); val.y = (unsigned)e2 | ((unsigned)e3<<16);
      *(uint2*)&Us[l][i4*4] = val;
    }
    __syncthreads();
    #pragma unroll
    for (int ks = 0; ks < 2; ++ks){
      int kk = ks*32 + quad*8;
      bf16x8 af[4], bv[4];
      #pragma unroll
      for (int mt=0;mt<4;++mt) af[mt] = *(const bf16x8*)&Ws[mt*16+ln][kk];
      #pragma unroll
      for (int nt=0;nt<4;++nt) bv[nt] = *(const bf16x8*)&Us[w*64+nt*16+ln][kk];
      #pragma unroll
      for (int mt=0;mt<4;++mt)
        #pragma unroll
        for (int nt=0;nt<4;++nt)
          acc[mt][nt] = __builtin_amdgcn_mfma_f32_16x16x32_bf16(af[mt], bv[nt], acc[mt][nt],0,0,0);
    }
  }
  #pragma unroll
  for (int mt=0;mt<4;++mt){
    #pragma unroll
    for (int reg=0;reg<4;++reg){
      int o = o0 + mt*16 + quad*4 + reg;
      float bo = bias[o];
      const float* arow = Ax + ((size_t)b*256 + o)*1024;
      unsigned short* grow = G + ((size_t)b*256 + o)*1024;
      #pragma unroll
      for (int nt=0;nt<4;++nt){
        int l = l0 + w*64 + nt*16 + ln;
        float v = acc[mt][nt][reg] + bo + arow[l];
        float g = tanhf(v)*sigmoidf_(v);
        grow[l] = f2bf(g);
      }
    }
  }
}

// ---------------- K7: out1 = lin1@g + b1 + x1 ; out2 = lin2@g + b2  (bf16 MFMA, dual acc)
__global__ __launch_bounds__(256,2) void k_out(const unsigned short* __restrict__ G,
        const float* __restrict__ W1, const float* __restrict__ b1,
        const float* __restrict__ W2, const float* __restrict__ b2,
        const float* __restrict__ Ax, float* __restrict__ out){
  __shared__ unsigned short W1s[64][72];
  __shared__ unsigned short W2s[64][72];
  __shared__ unsigned short Us[256][72];
  const int tid = threadIdx.x;
  const int l0 = blockIdx.x * 256;
  const int o0 = blockIdx.y * 64;
  const int b  = blockIdx.z;
  const int lane = tid & 63, w = tid>>6, ln = lane&15, quad = lane>>4;
  f32x4 acc1[4][4] = {};
  f32x4 acc2[4][4] = {};
  for (int ch = 0; ch < 4; ++ch){
    int ic0 = ch*64;
    __syncthreads();
    {
      int o = tid & 63;
      int i = (tid >> 6) * 16;
      const float* w1src = W1 + (size_t)(o0+o)*256 + ic0 + i;
      const float* w2src = W2 + (size_t)(o0+o)*256 + ic0 + i;
      unsigned pk[8];
      #pragma unroll
      for (int r=0;r<8;++r) pk[r] = (unsigned)f2bf(w1src[2*r]) | ((unsigned)f2bf(w1src[2*r+1])<<16);
      uint4* dst1 = (uint4*)&W1s[o][i];
      dst1[0] = make_uint4(pk[0],pk[1],pk[2],pk[3]);
      dst1[1] = make_uint4(pk[4],pk[5],pk[6],pk[7]);
      #pragma unroll
      for (int r=0;r<8;++r) pk[r] = (unsigned)f2bf(w2src[2*r]) | ((unsigned)f2bf(w2src[2*r+1])<<16);
      uint4* dst2 = (uint4*)&W2s[o][i];
      dst2[0] = make_uint4(pk[0],pk[1],pk[2],pk[3]);
      dst2[1] = make_uint4(pk[4],pk[5],pk[6],pk[7]);
    }
    #pragma unroll
    for (int it = 0; it < 16; ++it){
      int i4 = (tid>>6) + 4*(it&3);
      int l  = (it>>2)*64 + (tid&63);
      const unsigned short* usrc = G + ((size_t)b*256 + ic0 + i4*4)*1024 + l0 + l;
      unsigned short e0 = usrc[0], e1 = usrc[1024], e2 = usrc[2048], e3 = usrc[3072];
      uint2 val; val.x = (unsigned)e0 | ((unsigned)e1<<16); val.y = (unsigned)e2 | ((unsigned)e3<<16);
      *(uint2*)&Us[l][i4*4] = val;
    }
    __syncthreads();
    #pragma unroll
    for (int ks = 0; ks < 2; ++ks){
      int kk = ks*32 + quad*8;
      bf16x8 bv[4];
      #pragma unroll
      for (int nt=0;nt<4;++nt) bv[nt] = *(const bf16x8*)&Us[w*64+nt*16+ln][kk];
      #pragma unroll
      for (int mt=0;mt<4;++mt){
        bf16x8 a1 = *(const bf16x8*)&W1s[mt*16+ln][kk];
        #pragma unroll
        for (int nt=0;nt<4;++nt)
          acc1[mt][nt] = __builtin_amdgcn_mfma_f32_16x16x32_bf16(a1, bv[nt], acc1[mt][nt],0,0,0);
      }
      #pragma unroll
      for (int mt=0;mt<4;++mt){
        bf16x8 a2 = *(const bf16x8*)&W2s[mt*16+ln][kk];
        #pragma unroll
        for (int nt=0;nt<4;++nt)
          acc2[mt][nt] = __builtin_amdgcn_mfma_f32_16x16x32_bf16(a2, bv[nt], acc2[mt][nt],0,0,0);
      }
    }
  }
  #pragma unroll
  for (int mt=0;mt<4;++mt){
    #pragma unroll
    for (int reg=0;reg<4;++reg){
      int o = o0 + mt*16 + quad*4 + reg;
      float bo1 = b1[o], bo2 = b2[o];
      const float* arow = Ax + ((size_t)b*256 + o)*1024;
      float* o1row = out + ((size_t)b*256 + o)*1024;
      float* o2row = o1row + BHLq;
      #pragma unroll
      for (int nt=0;nt<4;++nt){
        int l = l0 + w*64 + nt*16 + ln;
        o1row[l] = acc1[mt][nt][reg] + bo1 + arow[l];
        o2row[l] = acc2[mt][nt][reg] + bo2;
      }
    }
  }
}

extern "C" void kernel_launch(void* const* d_in, const int* in_sizes, int n_in,
                              void* d_out, int out_size, void* d_ws, size_t ws_size,
                              hipStream_t stream){
  const float* x      = (const float*)d_in[0];
  const int*   t      = (const int*)  d_in[1];
  const float* ada_w  = (const float*)d_in[2];
  const float* ada_b  = (const float*)d_in[3];
  const float* norm_w = (const float*)d_in[4];
  const float* norm_b = (const float*)d_in[5];
  const float* log_dt = (const float*)d_in[6];
  const float* A_re   = (const float*)d_in[7];
  const float* A_im   = (const float*)d_in[8];
  const float* C_re   = (const float*)d_in[9];
  const float* C_im   = (const float*)d_in[10];
  const float* Dp     = (const float*)d_in[11];
  const float* out_w  = (const float*)d_in[12];
  const float* out_b  = (const float*)d_in[13];
  const float* lin1_w = (const float*)d_in[14];
  const float* lin1_b = (const float*)d_in[15];
  const float* lin2_w = (const float*)d_in[16];
  const float* lin2_b = (const float*)d_in[17];

  float* Ax            = (float*)d_ws;                     // x1 fp32, BHL
  unsigned short* Zb   = (unsigned short*)(Ax + BHLq);     // z bf16, BHL
  unsigned short* Cb   = Zb + BHLq;                        // gelu(y) bf16, BHL
  float* Kbuf          = (float*)(Cb + BHLq);              // 2*H*L fp32
  float* scsh          = Kbuf + 2*HLq;                     // B*2048 fp32
  unsigned short* Sb   = (unsigned short*)(scsh + Bq*2048);// silu(emb) bf16, B*1024
  unsigned short* Gb   = Zb;                               // gate g bf16 aliases dead z
  float* out           = (float*)d_out;

  k_emb   <<<Bq, 256, 0, stream>>>(t, Sb);
  k_adaG  <<<32, 256, 0, stream>>>(Sb, ada_w, ada_b, scsh);
  k_adaln <<<Bq*Hq, 256, 0, stream>>>(x, scsh, Ax);
  k_chln  <<<dim3(4, Bq), 256, 0, stream>>>(Ax, norm_w, norm_b, Zb);
  k_ssmk  <<<dim3(4, Hq), 256, 0, stream>>>(log_dt, A_re, A_im, C_re, C_im, Kbuf);
  k_conv  <<<dim3(2, Hq), 256, 0, stream>>>(Zb, Kbuf, Dp, Cb);
  k_gate  <<<dim3(4, 4, Bq), 256, 0, stream>>>(Cb, out_w, out_b, Ax, Gb);
  k_out   <<<dim3(4, 4, Bq), 256, 0, stream>>>(Gb, lin1_w, lin1_b, lin2_w, lin2_b, Ax, out);
}